// Round 8
// baseline (1430.565 us; speedup 1.0000x reference)
//
#include <hip/hip_runtime.h>

typedef unsigned short ushortT;
typedef __attribute__((ext_vector_type(8))) short short8;
typedef __attribute__((ext_vector_type(4))) float float4v;

__device__ __forceinline__ float bf2f(unsigned short h) {
    unsigned u = ((unsigned)h) << 16;
    return __builtin_bit_cast(float, u);
}
__device__ __forceinline__ unsigned short f2bf(float f) {
    unsigned u = __builtin_bit_cast(unsigned, f);
    u = u + 0x7fffu + ((u >> 16) & 1u);
    return (unsigned short)(u >> 16);
}
__device__ __forceinline__ void unpack_add(uint4 v, float a[8]) {
    a[0] += bf2f((ushortT)v.x); a[1] += bf2f((ushortT)(v.x >> 16));
    a[2] += bf2f((ushortT)v.y); a[3] += bf2f((ushortT)(v.y >> 16));
    a[4] += bf2f((ushortT)v.z); a[5] += bf2f((ushortT)(v.z >> 16));
    a[6] += bf2f((ushortT)v.w); a[7] += bf2f((ushortT)(v.w >> 16));
}

// 8-element row load; f32 flag folds at compile time
__device__ __forceinline__ void loadc8(bool f32, const void* p, size_t off, float o[8]) {
    if (f32) {
        const float* q = (const float*)p + off;
        float4 a = *(const float4*)q;
        float4 b = *(const float4*)(q + 4);
        o[0] = a.x; o[1] = a.y; o[2] = a.z; o[3] = a.w;
        o[4] = b.x; o[5] = b.y; o[6] = b.z; o[7] = b.w;
    } else {
        uint4 v = *(const uint4*)((const ushortT*)p + off);
        unsigned uu[4] = {v.x, v.y, v.z, v.w};
        #pragma unroll
        for (int j = 0; j < 8; j++) o[j] = bf2f((unsigned short)(uu[j >> 1] >> ((j & 1) * 16)));
    }
}

// ---------------- combined weight build: Wc[n][seg*512+g*128+dl | 4*DIN+d] ----------------
__global__ __launch_bounds__(256) void build_wc(const float* __restrict__ Ws, const float* __restrict__ Wb,
                                                ushortT* __restrict__ Wc, int dout, int din) {
    int idx = blockIdx.x * 256 + threadIdx.x;
    int kw = 5 * din;
    if (idx >= dout * kw) return;
    int n = idx / kw, c = idx % kw;
    float v;
    if (c < 4 * din) {
        int seg = c >> 9;
        int rem = c & 511;
        int g = rem >> 7;
        int dl = rem & 127;
        v = Ws[(size_t)n * 4 * din + 4 * (seg * 128 + dl) + g];
    } else {
        v = Wb[(size_t)n * din + (c - 4 * din)];
    }
    Wc[idx] = f2bf(v);
}

// ---------------- per-row LN stats for f32 x (+ optional bf16 mirror) ----------------

__global__ __launch_bounds__(256) void stats_f32(const float* __restrict__ X, float2* __restrict__ ST,
                                                 ushortT* __restrict__ xb, int n) {
    int wid = (blockIdx.x * 256 + threadIdx.x) >> 6;
    int lane = threadIdx.x & 63;
    if (wid >= n) return;
    float2 v = *(const float2*)(X + (size_t)wid * 128 + lane * 2);
    if (xb) {
        unsigned pk = (unsigned)f2bf(v.x) | ((unsigned)f2bf(v.y) << 16);
        *(unsigned*)(xb + (size_t)wid * 128 + lane * 2) = pk;
    }
    float s = v.x + v.y, ss = v.x * v.x + v.y * v.y;
    #pragma unroll
    for (int d = 1; d < 64; d <<= 1) { s += __shfl_xor(s, d); ss += __shfl_xor(ss, d); }
    if (lane == 0) ST[wid] = make_float2(s, ss);
}

// ---------------- CSR build via 2-level bucketing (bucket = dst>>8, 256 nodes) ----------------

__global__ __launch_bounds__(256) void zero_ints(int* p, int n) {
    int i = blockIdx.x * 256 + threadIdx.x;
    if (i < n) p[i] = 0;
}

__global__ __launch_bounds__(256) void bucket_count(const int* __restrict__ dst, int* __restrict__ bc,
                                                    int E, int n, int nb) {
    __shared__ int lh[512];
    int tid = threadIdx.x;
    for (int i = tid; i < nb; i += 256) lh[i] = 0;
    __syncthreads();
    for (int e = blockIdx.x * 256 + tid; e < E; e += gridDim.x * 256) {
        int d = dst[e];
        if ((unsigned)d < (unsigned)n) atomicAdd(&lh[d >> 8], 1);
    }
    __syncthreads();
    for (int i = tid; i < nb; i += 256) if (lh[i]) atomicAdd(&bc[i], lh[i]);
}

__device__ __forceinline__ int wave_incl_scan(int v, int lane) {
    #pragma unroll
    for (int d = 1; d < 64; d <<= 1) {
        int o = __shfl_up(v, d);
        if (lane >= d) v += o;
    }
    return v;
}

__global__ __launch_bounds__(64) void bucket_scan(const int* __restrict__ bc, int* __restrict__ boff,
                                                  int* __restrict__ curb, int nb, int E) {
    int lane = threadIdx.x;
    int carry = 0;
    for (int base = 0; base < nb; base += 64) {
        int i = base + lane;
        int v = (i < nb) ? bc[i] : 0;
        int incl = wave_incl_scan(v, lane);
        int excl = carry + incl - v;
        if (i < nb) { boff[i] = excl; curb[i] = excl; }
        carry += __shfl(incl, 63);
    }
    if (lane == 0) boff[nb] = E;
}

__global__ __launch_bounds__(256) void bucket_fill(const int* __restrict__ src, const int* __restrict__ dst,
                                                   int* __restrict__ curb, uint2* __restrict__ ebuf, int E, int n) {
    int e = blockIdx.x * 256 + threadIdx.x;
    if (e < E) {
        int d = dst[e];
        if ((unsigned)d < (unsigned)n) {
            int b = d >> 8;
            int p = atomicAdd(&curb[b], 1);
            ebuf[p] = make_uint2((unsigned)src[e], (unsigned)d);
        }
    }
}

// per-bucket node histogram -> cnt (coalesced; replaces random-atomic hist)
__global__ __launch_bounds__(256) void node_count(const uint2* __restrict__ ebuf, const int* __restrict__ boff,
                                                  int* __restrict__ cnt, int n) {
    __shared__ int lc[256];
    int b = blockIdx.x, tid = threadIdx.x;
    lc[tid] = 0;
    __syncthreads();
    int s0 = boff[b], s1 = boff[b + 1];
    for (int i = s0 + tid; i < s1; i += 256) atomicAdd(&lc[ebuf[i].y & 255], 1);
    __syncthreads();
    int node = (b << 8) + tid;
    if (node < n) cnt[node] = lc[tid];
}

__global__ __launch_bounds__(256) void scanA(const int* __restrict__ cnt, int* __restrict__ out,
                                             int* __restrict__ bsum, int n) {
    __shared__ int wtot[4];
    int tid = threadIdx.x, blk = blockIdx.x;
    int base = blk * 1024 + tid * 4;
    int e[4];
    #pragma unroll
    for (int j = 0; j < 4; j++) { int idx = base + j; e[j] = (idx < n) ? cnt[idx] : 0; }
    int s = e[0] + e[1] + e[2] + e[3];
    int lane = tid & 63, w = tid >> 6;
    int incl = wave_incl_scan(s, lane);
    if (lane == 63) wtot[w] = incl;
    __syncthreads();
    int woff = 0;
    for (int i = 0; i < w; i++) woff += wtot[i];
    int run = woff + incl - s;
    #pragma unroll
    for (int j = 0; j < 4; j++) { int idx = base + j; if (idx < n) out[idx] = run; run += e[j]; }
    if (tid == 0) bsum[blk] = wtot[0] + wtot[1] + wtot[2] + wtot[3];
}

__global__ __launch_bounds__(64) void scanB(int* bsum, int nb) {
    int lane = threadIdx.x;
    int carry = 0;
    for (int base = 0; base < nb; base += 64) {
        int i = base + lane;
        int v = (i < nb) ? bsum[i] : 0;
        int incl = wave_incl_scan(v, lane);
        if (i < nb) bsum[i] = carry + incl - v;
        carry += __shfl(incl, 63);
    }
}

__global__ __launch_bounds__(256) void scanC(int* __restrict__ out, const int* __restrict__ bsum, int n, int E) {
    int blk = blockIdx.x, tid = threadIdx.x;
    int off = bsum[blk];
    int base = blk * 1024 + tid * 4;
    #pragma unroll
    for (int j = 0; j < 4; j++) { int idx = base + j; if (idx < n) out[idx] += off; }
    if (blk == 0 && tid == 0) out[n] = E;
}

__global__ __launch_bounds__(256) void dinv_kernel(const int* __restrict__ rowptr, float* __restrict__ dinv, int n) {
    int i = blockIdx.x * 256 + threadIdx.x;
    if (i < n) {
        int deg = rowptr[i + 1] - rowptr[i] + 1;  // +1 self loop
        dinv[i] = rsqrtf((float)max(deg, 1));
    }
}

// per-bucket scatter with LDS cursors; colv active span per bucket ~16KB (L2-resident)
__global__ __launch_bounds__(256) void final_fill(const uint2* __restrict__ ebuf, const int* __restrict__ boff,
                                                  const int* __restrict__ rowptr, int* __restrict__ colv, int n) {
    __shared__ int lcur[256];
    int b = blockIdx.x, tid = threadIdx.x;
    int node = (b << 8) + tid;
    lcur[tid] = (node < n) ? rowptr[node] : 0;
    __syncthreads();
    int s0 = boff[b], s1 = boff[b + 1];
    for (int i = s0 + tid; i < s1; i += 256) {
        uint2 pr = ebuf[i];
        int p = atomicAdd(&lcur[pr.y & 255], 1);
        colv[p] = (int)pr.x;
    }
}

// ---------------- fused FastKAN transform ----------------
// No LDS. ONE 16-row group per wave (64 rows/block) for TLP. K-order matches Wc.
// Output rows PRE-SCALED by dinv[row].
template <int NSEG, int DOUT, int F32MASK>
__global__ __launch_bounds__(256) void fkan_kernel(
    const void* __restrict__ X0, int s0,
    const void* __restrict__ X1, int s1,
    const void* __restrict__ X2, int s2,
    const float2* __restrict__ ST0, const float2* __restrict__ ST1, const float2* __restrict__ ST2,
    const float* __restrict__ lng, const float* __restrict__ lnb,
    const ushortT* __restrict__ Wc,
    const float* __restrict__ bs, const float* __restrict__ bb,
    const float* __restrict__ dinv,
    ushortT* __restrict__ H, int hstride, int nrows) {
    constexpr int DIN = NSEG * 128;
    constexpr int KW = 5 * DIN;
    constexpr int NT = (DOUT + 15) / 16;
    int tid = threadIdx.x;
    int w = tid >> 6, lane = tid & 63;
    int m = lane & 15, q = lane >> 4;
    int base = blockIdx.x * 64 + w * 16;
    int r = min(base + m, nrows - 1);

    float mu, sc;
    {
        float2 st = ST0[r]; float sum = st.x, ssq = st.y;
        if (NSEG == 3) { float2 t1 = ST1[r]; sum += t1.x; ssq += t1.y; float2 t2 = ST2[r]; sum += t2.x; ssq += t2.y; }
        mu = sum * (1.0f / DIN);
        float var = ssq * (1.0f / DIN) - mu * mu;
        sc = rsqrtf(fmaxf(var, 0.0f) + 1e-5f);
    }

    float4v acc[NT];
    #pragma unroll
    for (int t = 0; t < NT; t++) acc[t] = (float4v){0.f, 0.f, 0.f, 0.f};

    const float G[4] = {-2.f, -2.f / 3.f, 2.f / 3.f, 2.f};

    // ---- RBF region ----
    #pragma unroll
    for (int seg = 0; seg < NSEG; seg++) {
        const void* Xp = (seg == 0) ? X0 : (seg == 1) ? X1 : X2;
        int str = (seg == 0) ? s0 : (seg == 1) ? s1 : s2;
        bool f32 = ((F32MASK >> seg) & 1) != 0;
        #pragma unroll
        for (int i = 0; i < 4; i++) {
            int d0 = i * 32 + q * 8;
            float xa[8];
            loadc8(f32, Xp, (size_t)r * str + d0, xa);
            float4 gv0 = *(const float4*)(lng + seg * 128 + d0);
            float4 gv1 = *(const float4*)(lng + seg * 128 + d0 + 4);
            float4 bv0 = *(const float4*)(lnb + seg * 128 + d0);
            float4 bv1 = *(const float4*)(lnb + seg * 128 + d0 + 4);
            float gvs[8] = {gv0.x, gv0.y, gv0.z, gv0.w, gv1.x, gv1.y, gv1.z, gv1.w};
            float bvs[8] = {bv0.x, bv0.y, bv0.z, bv0.w, bv1.x, bv1.y, bv1.z, bv1.w};
            float za[8];
            #pragma unroll
            for (int j = 0; j < 8; j++) za[j] = (xa[j] - mu) * sc * gvs[j] + bvs[j];
            #pragma unroll
            for (int g = 0; g < 4; g++) {
                short8 af;
                #pragma unroll
                for (int j = 0; j < 8; j++) {
                    float d = (za[j] - G[g]) * 0.75f;  // 1/DENOM = 3/4
                    af[j] = (short)f2bf(__expf(-d * d));
                }
                int kbase = seg * 512 + g * 128 + i * 32;
                #pragma unroll
                for (int t = 0; t < NT; t++) {
                    int n = t * 16 + m;
                    short8 bfr = (short8){0, 0, 0, 0, 0, 0, 0, 0};
                    if ((DOUT % 16 == 0) || (n < DOUT))
                        bfr = *(const short8*)(Wc + (size_t)n * KW + kbase + q * 8);
                    acc[t] = __builtin_amdgcn_mfma_f32_16x16x32_bf16(af, bfr, acc[t], 0, 0, 0);
                }
            }
        }
    }

    // ---- SiLU region ----
    #pragma unroll
    for (int seg = 0; seg < NSEG; seg++) {
        const void* Xp = (seg == 0) ? X0 : (seg == 1) ? X1 : X2;
        int str = (seg == 0) ? s0 : (seg == 1) ? s1 : s2;
        bool f32 = ((F32MASK >> seg) & 1) != 0;
        #pragma unroll
        for (int i = 0; i < 4; i++) {
            int c = i * 32 + q * 8;
            float xa[8];
            loadc8(f32, Xp, (size_t)r * str + c, xa);
            short8 af;
            #pragma unroll
            for (int j = 0; j < 8; j++) {
                float sa = 1.0f / (1.0f + __expf(-xa[j]));
                af[j] = (short)f2bf(xa[j] * sa);
            }
            int kbase = 4 * DIN + seg * 128 + i * 32;
            #pragma unroll
            for (int t = 0; t < NT; t++) {
                int n = t * 16 + m;
                short8 bfr = (short8){0, 0, 0, 0, 0, 0, 0, 0};
                if ((DOUT % 16 == 0) || (n < DOUT))
                    bfr = *(const short8*)(Wc + (size_t)n * KW + kbase + q * 8);
                acc[t] = __builtin_amdgcn_mfma_f32_16x16x32_bf16(af, bfr, acc[t], 0, 0, 0);
            }
        }
    }

    // epilogue: C/D layout col=lane&15, row=quad*4+rr ; store h*dinv[row]
    float dv[4];
    #pragma unroll
    for (int rr = 0; rr < 4; rr++) {
        int row = base + q * 4 + rr;
        dv[rr] = (row < nrows) ? dinv[row] : 0.f;
    }
    #pragma unroll
    for (int t = 0; t < NT; t++) {
        int col = t * 16 + m;
        if ((DOUT % 16 == 0) || (col < DOUT)) {
            float bias = bs[col] + bb[col];
            #pragma unroll
            for (int rr = 0; rr < 4; rr++) {
                int row = base + q * 4 + rr;
                if (row < nrows) H[(size_t)row * hstride + col] = f2bf((acc[t][rr] + bias) * dv[rr]);
            }
        }
    }
}

// ---------------- aggregation: wave per node, 4 edges in flight ----------------
// H is pre-scaled by dinv[src]. out = dinv[wid]*(H[wid] + sum_nbr H[s]) + bg.

__global__ __launch_bounds__(256) void agg128_kernel(
    const ushortT* __restrict__ H, ushortT* __restrict__ OUT,
    const float* __restrict__ bg, const int* __restrict__ rowptr,
    const int* __restrict__ colv, const float* __restrict__ dinv,
    float2* __restrict__ STout, int n) {
    int wid = (blockIdx.x * 256 + threadIdx.x) >> 6;
    int lane = threadIdx.x & 63;
    if (wid >= n) return;
    int g = lane >> 4, t = lane & 15;
    float di = dinv[wid];
    float a[8] = {0.f, 0.f, 0.f, 0.f, 0.f, 0.f, 0.f, 0.f};
    if (g == 0) unpack_add(*(const uint4*)(H + (size_t)wid * 128 + t * 8), a);  // self
    int e0 = rowptr[wid], e1 = rowptr[wid + 1];
    for (int e = e0 + g; e < e1; e += 4) {
        int s = colv[e];
        unpack_add(*(const uint4*)(H + (size_t)s * 128 + t * 8), a);
    }
    #pragma unroll
    for (int j = 0; j < 8; j++) {
        a[j] += __shfl_xor(a[j], 16);
        a[j] += __shfl_xor(a[j], 32);
    }
    if (g == 0) {
        float4 b0 = *(const float4*)(bg + t * 8);
        float4 b1 = *(const float4*)(bg + t * 8 + 4);
        float bgs[8] = {b0.x, b0.y, b0.z, b0.w, b1.x, b1.y, b1.z, b1.w};
        unsigned rb[8];
        float s = 0.f, ss = 0.f;
        #pragma unroll
        for (int j = 0; j < 8; j++) {
            float o = di * a[j] + bgs[j];
            rb[j] = f2bf(o);
            float back = bf2f((unsigned short)rb[j]);
            s += back; ss += back * back;
        }
        uint4 pk;
        pk.x = rb[0] | (rb[1] << 16);
        pk.y = rb[2] | (rb[3] << 16);
        pk.z = rb[4] | (rb[5] << 16);
        pk.w = rb[6] | (rb[7] << 16);
        *(uint4*)(OUT + (size_t)wid * 128 + t * 8) = pk;
        #pragma unroll
        for (int d = 1; d < 16; d <<= 1) { s += __shfl_xor(s, d); ss += __shfl_xor(ss, d); }
        if (t == 0) STout[wid] = make_float2(s, ss);
    }
}

// H stride 64 (cols 47..63 junk). 8 edges in flight.
__global__ __launch_bounds__(256) void agg47_kernel(
    const ushortT* __restrict__ H, float* __restrict__ OUT,
    const float* __restrict__ bg, const int* __restrict__ rowptr,
    const int* __restrict__ colv, const float* __restrict__ dinv, int n) {
    int wid = (blockIdx.x * 256 + threadIdx.x) >> 6;
    int lane = threadIdx.x & 63;
    if (wid >= n) return;
    int g = lane >> 3, t = lane & 7;
    float di = dinv[wid];
    float a[8] = {0.f, 0.f, 0.f, 0.f, 0.f, 0.f, 0.f, 0.f};
    if (g == 0) unpack_add(*(const uint4*)(H + (size_t)wid * 64 + t * 8), a);  // self
    int e0 = rowptr[wid], e1 = rowptr[wid + 1];
    for (int e = e0 + g; e < e1; e += 8) {
        int s = colv[e];
        unpack_add(*(const uint4*)(H + (size_t)s * 64 + t * 8), a);
    }
    #pragma unroll
    for (int j = 0; j < 8; j++) {
        a[j] += __shfl_xor(a[j], 8);
        a[j] += __shfl_xor(a[j], 16);
        a[j] += __shfl_xor(a[j], 32);
    }
    if (g == 0) {
        #pragma unroll
        for (int j = 0; j < 8; j++) {
            int c = t * 8 + j;
            if (c < 47) OUT[(size_t)wid * 47 + c] = di * a[j] + bg[c];
        }
    }
}

// ---------------- launcher ----------------

extern "C" void kernel_launch(void* const* d_in, const int* in_sizes, int n_in,
                              void* d_out, int out_size, void* d_ws, size_t ws_size,
                              hipStream_t stream) {
    const float* x = (const float*)d_in[0];
    const int* ei = (const int*)d_in[1];
    const float* lng0 = (const float*)d_in[2];
    const float* lnb0 = (const float*)d_in[3];
    const float* Ws0 = (const float*)d_in[4];
    const float* bs0 = (const float*)d_in[5];
    const float* Wb0 = (const float*)d_in[6];
    const float* bb0 = (const float*)d_in[7];
    const float* bg0 = (const float*)d_in[8];
    const float* lng1 = (const float*)d_in[9];
    const float* lnb1 = (const float*)d_in[10];
    const float* Ws1 = (const float*)d_in[11];
    const float* bs1 = (const float*)d_in[12];
    const float* Wb1 = (const float*)d_in[13];
    const float* bb1 = (const float*)d_in[14];
    const float* bg1 = (const float*)d_in[15];
    const float* lng2 = (const float*)d_in[16];
    const float* lnb2 = (const float*)d_in[17];
    const float* Ws2 = (const float*)d_in[18];
    const float* bs2 = (const float*)d_in[19];
    const float* Wb2 = (const float*)d_in[20];
    const float* bb2 = (const float*)d_in[21];
    const float* bg2 = (const float*)d_in[22];

    const int N = in_sizes[0] / 128;
    const int E = in_sizes[1] / 2;
    const int NB = (N + 255) >> 8;  // buckets of 256 nodes (<=512 for N<=128K)

    char* wsp = (char*)d_ws;
    size_t off = 0;
    auto alloc = [&](size_t bytes) {
        off = (off + 255) & ~(size_t)255;
        void* p = wsp + off;
        off += bytes;
        return p;
    };
    int* cnt = (int*)alloc((size_t)N * 4);
    int* rowptr = (int*)alloc((size_t)(N + 1) * 4);
    int* bsum = (int*)alloc(1024 * 4);
    int* bc = (int*)alloc((size_t)NB * 4);
    int* boff = (int*)alloc((size_t)(NB + 1) * 4);
    int* curb = (int*)alloc((size_t)NB * 4);
    int* colv = (int*)alloc((size_t)E * 4);
    float* dinvv = (float*)alloc((size_t)N * 4);
    ushortT* hbuf = (ushortT*)alloc((size_t)N * 128 * 2);
    ushortT* a1 = (ushortT*)alloc((size_t)N * 128 * 2);
    ushortT* a2 = (ushortT*)alloc((size_t)N * 128 * 2);
    float2* stx = (float2*)alloc((size_t)N * 8);
    float2* st1 = (float2*)alloc((size_t)N * 8);
    float2* st2 = (float2*)alloc((size_t)N * 8);
    ushortT* Wc0 = (ushortT*)alloc((size_t)128 * 640 * 2);
    ushortT* Wc1 = (ushortT*)alloc((size_t)128 * 640 * 2);
    ushortT* Wc2 = (ushortT*)alloc((size_t)47 * 1920 * 2);
    size_t off_base = off;
    ushortT* xb = (ushortT*)alloc((size_t)N * 128 * 2);  // bf16 mirror of x
    bool fits = (off <= ws_size);
    if (!fits) off = off_base;
    uint2* ebuf = (uint2*)hbuf;  // aliases hbuf: CSR build completes before fkan writes hbuf
    (void)n_in; (void)out_size;

    const int* srcp = ei;
    const int* dstp = ei + E;

    int gN = (N + 255) / 256;
    int gE = (E + 255) / 256;
    int nb = (N + 1023) / 1024;
    int gF = (N + 63) / 64;   // fkan blocks (64 rows)
    int gW = (N + 3) / 4;     // wave-per-node blocks

    build_wc<<<(128 * 640 + 255) / 256, 256, 0, stream>>>(Ws0, Wb0, Wc0, 128, 128);
    build_wc<<<(128 * 640 + 255) / 256, 256, 0, stream>>>(Ws1, Wb1, Wc1, 128, 128);
    build_wc<<<(47 * 1920 + 255) / 256, 256, 0, stream>>>(Ws2, Wb2, Wc2, 47, 384);

    // CSR build (bucketed)
    zero_ints<<<(NB + 255) / 256, 256, 0, stream>>>(bc, NB);
    bucket_count<<<256, 256, 0, stream>>>(dstp, bc, E, N, NB);
    bucket_scan<<<1, 64, 0, stream>>>(bc, boff, curb, NB, E);
    bucket_fill<<<gE, 256, 0, stream>>>(srcp, dstp, curb, ebuf, E, N);
    node_count<<<NB, 256, 0, stream>>>(ebuf, boff, cnt, N);
    scanA<<<nb, 256, 0, stream>>>(cnt, rowptr, bsum, N);
    scanB<<<1, 64, 0, stream>>>(bsum, nb);
    scanC<<<nb, 256, 0, stream>>>(rowptr, bsum, N, E);
    dinv_kernel<<<gN, 256, 0, stream>>>(rowptr, dinvv, N);
    final_fill<<<NB, 256, 0, stream>>>(ebuf, boff, rowptr, colv, N);
    stats_f32<<<gW, 256, 0, stream>>>(x, stx, fits ? xb : nullptr, N);

    // layer 1
    if (fits)
        fkan_kernel<1, 128, 0><<<gF, 256, 0, stream>>>(xb, 128, xb, 128, xb, 128, stx, stx, stx,
                                                       lng0, lnb0, Wc0, bs0, bb0, dinvv, hbuf, 128, N);
    else
        fkan_kernel<1, 128, 1><<<gF, 256, 0, stream>>>(x, 128, x, 128, x, 128, stx, stx, stx,
                                                       lng0, lnb0, Wc0, bs0, bb0, dinvv, hbuf, 128, N);
    agg128_kernel<<<gW, 256, 0, stream>>>(hbuf, a1, bg0, rowptr, colv, dinvv, st1, N);

    // layer 2
    fkan_kernel<1, 128, 0><<<gF, 256, 0, stream>>>(a1, 128, a1, 128, a1, 128, st1, st1, st1,
                                                   lng1, lnb1, Wc1, bs1, bb1, dinvv, hbuf, 128, N);
    agg128_kernel<<<gW, 256, 0, stream>>>(hbuf, a2, bg1, rowptr, colv, dinvv, st2, N);

    // layer 3 (hbuf stride 64)
    if (fits)
        fkan_kernel<3, 47, 0><<<gF, 256, 0, stream>>>(xb, 128, a1, 128, a2, 128, stx, st1, st2,
                                                      lng2, lnb2, Wc2, bs2, bb2, dinvv, hbuf, 64, N);
    else
        fkan_kernel<3, 47, 1><<<gF, 256, 0, stream>>>(x, 128, a1, 128, a2, 128, stx, st1, st2,
                                                      lng2, lnb2, Wc2, bs2, bb2, dinvv, hbuf, 64, N);
    agg47_kernel<<<gW, 256, 0, stream>>>(hbuf, (float*)d_out, bg2, rowptr, colv, dinvv, N);
}

// Round 9
// 916.725 us; speedup vs baseline: 1.5605x; 1.5605x over previous
//
#include <hip/hip_runtime.h>

typedef unsigned short ushortT;
typedef __attribute__((ext_vector_type(8))) short short8;
typedef __attribute__((ext_vector_type(4))) float float4v;

__device__ __forceinline__ float bf2f(unsigned short h) {
    unsigned u = ((unsigned)h) << 16;
    return __builtin_bit_cast(float, u);
}
__device__ __forceinline__ unsigned short f2bf(float f) {
    unsigned u = __builtin_bit_cast(unsigned, f);
    u = u + 0x7fffu + ((u >> 16) & 1u);
    return (unsigned short)(u >> 16);
}
__device__ __forceinline__ void unpack_add(uint4 v, float a[8]) {
    a[0] += bf2f((ushortT)v.x); a[1] += bf2f((ushortT)(v.x >> 16));
    a[2] += bf2f((ushortT)v.y); a[3] += bf2f((ushortT)(v.y >> 16));
    a[4] += bf2f((ushortT)v.z); a[5] += bf2f((ushortT)(v.z >> 16));
    a[6] += bf2f((ushortT)v.w); a[7] += bf2f((ushortT)(v.w >> 16));
}

// 8-element row load; f32 flag folds at compile time
__device__ __forceinline__ void loadc8(bool f32, const void* p, size_t off, float o[8]) {
    if (f32) {
        const float* q = (const float*)p + off;
        float4 a = *(const float4*)q;
        float4 b = *(const float4*)(q + 4);
        o[0] = a.x; o[1] = a.y; o[2] = a.z; o[3] = a.w;
        o[4] = b.x; o[5] = b.y; o[6] = b.z; o[7] = b.w;
    } else {
        uint4 v = *(const uint4*)((const ushortT*)p + off);
        unsigned uu[4] = {v.x, v.y, v.z, v.w};
        #pragma unroll
        for (int j = 0; j < 8; j++) o[j] = bf2f((unsigned short)(uu[j >> 1] >> ((j & 1) * 16)));
    }
}

// ---------------- combined weight build: Wc[n][seg*512+g*128+dl | 4*DIN+d] ----------------
__global__ __launch_bounds__(256) void build_wc(const float* __restrict__ Ws, const float* __restrict__ Wb,
                                                ushortT* __restrict__ Wc, int dout, int din) {
    int idx = blockIdx.x * 256 + threadIdx.x;
    int kw = 5 * din;
    if (idx >= dout * kw) return;
    int n = idx / kw, c = idx % kw;
    float v;
    if (c < 4 * din) {
        int seg = c >> 9;
        int rem = c & 511;
        int g = rem >> 7;
        int dl = rem & 127;
        v = Ws[(size_t)n * 4 * din + 4 * (seg * 128 + dl) + g];
    } else {
        v = Wb[(size_t)n * din + (c - 4 * din)];
    }
    Wc[idx] = f2bf(v);
}

// ---------------- per-row LN stats for f32 x (+ optional bf16 mirror) ----------------

__global__ __launch_bounds__(256) void stats_f32(const float* __restrict__ X, float2* __restrict__ ST,
                                                 ushortT* __restrict__ xb, int n) {
    int wid = (blockIdx.x * 256 + threadIdx.x) >> 6;
    int lane = threadIdx.x & 63;
    if (wid >= n) return;
    float2 v = *(const float2*)(X + (size_t)wid * 128 + lane * 2);
    if (xb) {
        unsigned pk = (unsigned)f2bf(v.x) | ((unsigned)f2bf(v.y) << 16);
        *(unsigned*)(xb + (size_t)wid * 128 + lane * 2) = pk;
    }
    float s = v.x + v.y, ss = v.x * v.x + v.y * v.y;
    #pragma unroll
    for (int d = 1; d < 64; d <<= 1) { s += __shfl_xor(s, d); ss += __shfl_xor(ss, d); }
    if (lane == 0) ST[wid] = make_float2(s, ss);
}

// ---------------- CSR build: 2-pass block-private counting sort by bucket (dst>>8) ----------------
// NBLK sort blocks, each owns a contiguous edge chunk. Zero global atomics.

#define NBLK 128
#define MAXB 512  // max buckets (N <= 131072)

__global__ __launch_bounds__(256) void s1_count(const int* __restrict__ dst, int* __restrict__ hmat,
                                                int E, int chunk, int n, int nb) {
    __shared__ int lh[MAXB];
    int b = blockIdx.x, tid = threadIdx.x;
    for (int i = tid; i < nb; i += 256) lh[i] = 0;
    __syncthreads();
    int e0 = b * chunk, e1 = min(e0 + chunk, E);
    for (int e = e0 + tid; e < e1; e += 256) {
        int d = dst[e];
        if ((unsigned)d < (unsigned)n) atomicAdd(&lh[d >> 8], 1);
    }
    __syncthreads();
    for (int i = tid; i < nb; i += 256) hmat[i * NBLK + b] = lh[i];
}

__global__ __launch_bounds__(256) void s3_place(const int* __restrict__ src, const int* __restrict__ dst,
                                                const int* __restrict__ hmatscan, uint2* __restrict__ ebuf,
                                                int E, int chunk, int n, int nb) {
    __shared__ int lcur[MAXB];
    int b = blockIdx.x, tid = threadIdx.x;
    for (int i = tid; i < nb; i += 256) lcur[i] = hmatscan[i * NBLK + b];
    __syncthreads();
    int e0 = b * chunk, e1 = min(e0 + chunk, E);
    for (int e = e0 + tid; e < e1; e += 256) {
        int d = dst[e];
        if ((unsigned)d < (unsigned)n) {
            int p = atomicAdd(&lcur[d >> 8], 1);
            ebuf[p] = make_uint2((unsigned)src[e], (unsigned)d);
        }
    }
}

__global__ __launch_bounds__(256) void boff_extract(const int* __restrict__ hmatscan, int* __restrict__ boff, int nb) {
    int i = blockIdx.x * 256 + threadIdx.x;
    if (i <= nb) boff[i] = hmatscan[i * NBLK];  // i==nb reads total (scanC wrote out[n])
}

// per-bucket node histogram -> cnt (L2-local; replaces random-atomic hist)
__global__ __launch_bounds__(256) void node_count(const uint2* __restrict__ ebuf, const int* __restrict__ boff,
                                                  int* __restrict__ cnt, int n) {
    __shared__ int lc[256];
    int b = blockIdx.x, tid = threadIdx.x;
    lc[tid] = 0;
    __syncthreads();
    int s0 = boff[b], s1 = boff[b + 1];
    for (int i = s0 + tid; i < s1; i += 256) atomicAdd(&lc[ebuf[i].y & 255], 1);
    __syncthreads();
    int node = (b << 8) + tid;
    if (node < n) cnt[node] = lc[tid];
}

__device__ __forceinline__ int wave_incl_scan(int v, int lane) {
    #pragma unroll
    for (int d = 1; d < 64; d <<= 1) {
        int o = __shfl_up(v, d);
        if (lane >= d) v += o;
    }
    return v;
}

__global__ __launch_bounds__(256) void scanA(const int* __restrict__ cnt, int* __restrict__ out,
                                             int* __restrict__ bsum, int n) {
    __shared__ int wtot[4];
    int tid = threadIdx.x, blk = blockIdx.x;
    int base = blk * 1024 + tid * 4;
    int e[4];
    #pragma unroll
    for (int j = 0; j < 4; j++) { int idx = base + j; e[j] = (idx < n) ? cnt[idx] : 0; }
    int s = e[0] + e[1] + e[2] + e[3];
    int lane = tid & 63, w = tid >> 6;
    int incl = wave_incl_scan(s, lane);
    if (lane == 63) wtot[w] = incl;
    __syncthreads();
    int woff = 0;
    for (int i = 0; i < w; i++) woff += wtot[i];
    int run = woff + incl - s;
    #pragma unroll
    for (int j = 0; j < 4; j++) { int idx = base + j; if (idx < n) out[idx] = run; run += e[j]; }
    if (tid == 0) bsum[blk] = wtot[0] + wtot[1] + wtot[2] + wtot[3];
}

__global__ __launch_bounds__(64) void scanB(int* bsum, int nb) {
    int lane = threadIdx.x;
    int carry = 0;
    for (int base = 0; base < nb; base += 64) {
        int i = base + lane;
        int v = (i < nb) ? bsum[i] : 0;
        int incl = wave_incl_scan(v, lane);
        if (i < nb) bsum[i] = carry + incl - v;
        carry += __shfl(incl, 63);
    }
}

__global__ __launch_bounds__(256) void scanC(int* __restrict__ out, const int* __restrict__ bsum, int n, int E) {
    int blk = blockIdx.x, tid = threadIdx.x;
    int off = bsum[blk];
    int base = blk * 1024 + tid * 4;
    #pragma unroll
    for (int j = 0; j < 4; j++) { int idx = base + j; if (idx < n) out[idx] += off; }
    if (blk == 0 && tid == 0) out[n] = E;
}

__global__ __launch_bounds__(256) void dinv_kernel(const int* __restrict__ rowptr, float* __restrict__ dinv, int n) {
    int i = blockIdx.x * 256 + threadIdx.x;
    if (i < n) {
        int deg = rowptr[i + 1] - rowptr[i] + 1;  // +1 self loop
        dinv[i] = rsqrtf((float)max(deg, 1));
    }
}

// per-bucket scatter with LDS cursors; colv active span per bucket ~16KB (L2-resident)
__global__ __launch_bounds__(256) void final_fill(const uint2* __restrict__ ebuf, const int* __restrict__ boff,
                                                  const int* __restrict__ rowptr, int* __restrict__ colv, int n) {
    __shared__ int lcur[256];
    int b = blockIdx.x, tid = threadIdx.x;
    int node = (b << 8) + tid;
    lcur[tid] = (node < n) ? rowptr[node] : 0;
    __syncthreads();
    int s0 = boff[b], s1 = boff[b + 1];
    for (int i = s0 + tid; i < s1; i += 256) {
        uint2 pr = ebuf[i];
        int p = atomicAdd(&lcur[pr.y & 255], 1);
        colv[p] = (int)pr.x;
    }
}

// ---------------- fused FastKAN transform ----------------
// No LDS. ONE 16-row group per wave (64 rows/block). K-order matches Wc.
// Output rows PRE-SCALED by dinv[row].
template <int NSEG, int DOUT, int F32MASK>
__global__ __launch_bounds__(256) void fkan_kernel(
    const void* __restrict__ X0, int s0,
    const void* __restrict__ X1, int s1,
    const void* __restrict__ X2, int s2,
    const float2* __restrict__ ST0, const float2* __restrict__ ST1, const float2* __restrict__ ST2,
    const float* __restrict__ lng, const float* __restrict__ lnb,
    const ushortT* __restrict__ Wc,
    const float* __restrict__ bs, const float* __restrict__ bb,
    const float* __restrict__ dinv,
    ushortT* __restrict__ H, int hstride, int nrows) {
    constexpr int DIN = NSEG * 128;
    constexpr int KW = 5 * DIN;
    constexpr int NT = (DOUT + 15) / 16;
    int tid = threadIdx.x;
    int w = tid >> 6, lane = tid & 63;
    int m = lane & 15, q = lane >> 4;
    int base = blockIdx.x * 64 + w * 16;
    int r = min(base + m, nrows - 1);

    float mu, sc;
    {
        float2 st = ST0[r]; float sum = st.x, ssq = st.y;
        if (NSEG == 3) { float2 t1 = ST1[r]; sum += t1.x; ssq += t1.y; float2 t2 = ST2[r]; sum += t2.x; ssq += t2.y; }
        mu = sum * (1.0f / DIN);
        float var = ssq * (1.0f / DIN) - mu * mu;
        sc = rsqrtf(fmaxf(var, 0.0f) + 1e-5f);
    }

    float4v acc[NT];
    #pragma unroll
    for (int t = 0; t < NT; t++) acc[t] = (float4v){0.f, 0.f, 0.f, 0.f};

    const float G[4] = {-2.f, -2.f / 3.f, 2.f / 3.f, 2.f};

    // ---- RBF region ----
    #pragma unroll
    for (int seg = 0; seg < NSEG; seg++) {
        const void* Xp = (seg == 0) ? X0 : (seg == 1) ? X1 : X2;
        int str = (seg == 0) ? s0 : (seg == 1) ? s1 : s2;
        bool f32 = ((F32MASK >> seg) & 1) != 0;
        #pragma unroll
        for (int i = 0; i < 4; i++) {
            int d0 = i * 32 + q * 8;
            float xa[8];
            loadc8(f32, Xp, (size_t)r * str + d0, xa);
            float4 gv0 = *(const float4*)(lng + seg * 128 + d0);
            float4 gv1 = *(const float4*)(lng + seg * 128 + d0 + 4);
            float4 bv0 = *(const float4*)(lnb + seg * 128 + d0);
            float4 bv1 = *(const float4*)(lnb + seg * 128 + d0 + 4);
            float gvs[8] = {gv0.x, gv0.y, gv0.z, gv0.w, gv1.x, gv1.y, gv1.z, gv1.w};
            float bvs[8] = {bv0.x, bv0.y, bv0.z, bv0.w, bv1.x, bv1.y, bv1.z, bv1.w};
            float za[8];
            #pragma unroll
            for (int j = 0; j < 8; j++) za[j] = (xa[j] - mu) * sc * gvs[j] + bvs[j];
            #pragma unroll
            for (int g = 0; g < 4; g++) {
                short8 af;
                #pragma unroll
                for (int j = 0; j < 8; j++) {
                    float d = (za[j] - G[g]) * 0.75f;  // 1/DENOM = 3/4
                    af[j] = (short)f2bf(__expf(-d * d));
                }
                int kbase = seg * 512 + g * 128 + i * 32;
                #pragma unroll
                for (int t = 0; t < NT; t++) {
                    int n = t * 16 + m;
                    short8 bfr = (short8){0, 0, 0, 0, 0, 0, 0, 0};
                    if ((DOUT % 16 == 0) || (n < DOUT))
                        bfr = *(const short8*)(Wc + (size_t)n * KW + kbase + q * 8);
                    acc[t] = __builtin_amdgcn_mfma_f32_16x16x32_bf16(af, bfr, acc[t], 0, 0, 0);
                }
            }
        }
    }

    // ---- SiLU region ----
    #pragma unroll
    for (int seg = 0; seg < NSEG; seg++) {
        const void* Xp = (seg == 0) ? X0 : (seg == 1) ? X1 : X2;
        int str = (seg == 0) ? s0 : (seg == 1) ? s1 : s2;
        bool f32 = ((F32MASK >> seg) & 1) != 0;
        #pragma unroll
        for (int i = 0; i < 4; i++) {
            int c = i * 32 + q * 8;
            float xa[8];
            loadc8(f32, Xp, (size_t)r * str + c, xa);
            short8 af;
            #pragma unroll
            for (int j = 0; j < 8; j++) {
                float sa = 1.0f / (1.0f + __expf(-xa[j]));
                af[j] = (short)f2bf(xa[j] * sa);
            }
            int kbase = 4 * DIN + seg * 128 + i * 32;
            #pragma unroll
            for (int t = 0; t < NT; t++) {
                int n = t * 16 + m;
                short8 bfr = (short8){0, 0, 0, 0, 0, 0, 0, 0};
                if ((DOUT % 16 == 0) || (n < DOUT))
                    bfr = *(const short8*)(Wc + (size_t)n * KW + kbase + q * 8);
                acc[t] = __builtin_amdgcn_mfma_f32_16x16x32_bf16(af, bfr, acc[t], 0, 0, 0);
            }
        }
    }

    // epilogue: C/D layout col=lane&15, row=quad*4+rr ; store h*dinv[row]
    float dv[4];
    #pragma unroll
    for (int rr = 0; rr < 4; rr++) {
        int row = base + q * 4 + rr;
        dv[rr] = (row < nrows) ? dinv[row] : 0.f;
    }
    #pragma unroll
    for (int t = 0; t < NT; t++) {
        int col = t * 16 + m;
        if ((DOUT % 16 == 0) || (col < DOUT)) {
            float bias = bs[col] + bb[col];
            #pragma unroll
            for (int rr = 0; rr < 4; rr++) {
                int row = base + q * 4 + rr;
                if (row < nrows) H[(size_t)row * hstride + col] = f2bf((acc[t][rr] + bias) * dv[rr]);
            }
        }
    }
}

// ---------------- aggregation: wave per node, 4 edges in flight ----------------
// H is pre-scaled by dinv[src]. out = dinv[wid]*(H[wid] + sum_nbr H[s]) + bg.

__global__ __launch_bounds__(256) void agg128_kernel(
    const ushortT* __restrict__ H, ushortT* __restrict__ OUT,
    const float* __restrict__ bg, const int* __restrict__ rowptr,
    const int* __restrict__ colv, const float* __restrict__ dinv,
    float2* __restrict__ STout, int n) {
    int wid = (blockIdx.x * 256 + threadIdx.x) >> 6;
    int lane = threadIdx.x & 63;
    if (wid >= n) return;
    int g = lane >> 4, t = lane & 15;
    float di = dinv[wid];
    float a[8] = {0.f, 0.f, 0.f, 0.f, 0.f, 0.f, 0.f, 0.f};
    if (g == 0) unpack_add(*(const uint4*)(H + (size_t)wid * 128 + t * 8), a);  // self
    int e0 = rowptr[wid], e1 = rowptr[wid + 1];
    for (int e = e0 + g; e < e1; e += 4) {
        int s = colv[e];
        unpack_add(*(const uint4*)(H + (size_t)s * 128 + t * 8), a);
    }
    #pragma unroll
    for (int j = 0; j < 8; j++) {
        a[j] += __shfl_xor(a[j], 16);
        a[j] += __shfl_xor(a[j], 32);
    }
    if (g == 0) {
        float4 b0 = *(const float4*)(bg + t * 8);
        float4 b1 = *(const float4*)(bg + t * 8 + 4);
        float bgs[8] = {b0.x, b0.y, b0.z, b0.w, b1.x, b1.y, b1.z, b1.w};
        unsigned rb[8];
        float s = 0.f, ss = 0.f;
        #pragma unroll
        for (int j = 0; j < 8; j++) {
            float o = di * a[j] + bgs[j];
            rb[j] = f2bf(o);
            float back = bf2f((unsigned short)rb[j]);
            s += back; ss += back * back;
        }
        uint4 pk;
        pk.x = rb[0] | (rb[1] << 16);
        pk.y = rb[2] | (rb[3] << 16);
        pk.z = rb[4] | (rb[5] << 16);
        pk.w = rb[6] | (rb[7] << 16);
        *(uint4*)(OUT + (size_t)wid * 128 + t * 8) = pk;
        #pragma unroll
        for (int d = 1; d < 16; d <<= 1) { s += __shfl_xor(s, d); ss += __shfl_xor(ss, d); }
        if (t == 0) STout[wid] = make_float2(s, ss);
    }
}

// H stride 64 (cols 47..63 junk). 8 edges in flight.
__global__ __launch_bounds__(256) void agg47_kernel(
    const ushortT* __restrict__ H, float* __restrict__ OUT,
    const float* __restrict__ bg, const int* __restrict__ rowptr,
    const int* __restrict__ colv, const float* __restrict__ dinv, int n) {
    int wid = (blockIdx.x * 256 + threadIdx.x) >> 6;
    int lane = threadIdx.x & 63;
    if (wid >= n) return;
    int g = lane >> 3, t = lane & 7;
    float di = dinv[wid];
    float a[8] = {0.f, 0.f, 0.f, 0.f, 0.f, 0.f, 0.f, 0.f};
    if (g == 0) unpack_add(*(const uint4*)(H + (size_t)wid * 64 + t * 8), a);  // self
    int e0 = rowptr[wid], e1 = rowptr[wid + 1];
    for (int e = e0 + g; e < e1; e += 8) {
        int s = colv[e];
        unpack_add(*(const uint4*)(H + (size_t)s * 64 + t * 8), a);
    }
    #pragma unroll
    for (int j = 0; j < 8; j++) {
        a[j] += __shfl_xor(a[j], 8);
        a[j] += __shfl_xor(a[j], 16);
        a[j] += __shfl_xor(a[j], 32);
    }
    if (g == 0) {
        #pragma unroll
        for (int j = 0; j < 8; j++) {
            int c = t * 8 + j;
            if (c < 47) OUT[(size_t)wid * 47 + c] = di * a[j] + bg[c];
        }
    }
}

// ---------------- launcher ----------------

extern "C" void kernel_launch(void* const* d_in, const int* in_sizes, int n_in,
                              void* d_out, int out_size, void* d_ws, size_t ws_size,
                              hipStream_t stream) {
    const float* x = (const float*)d_in[0];
    const int* ei = (const int*)d_in[1];
    const float* lng0 = (const float*)d_in[2];
    const float* lnb0 = (const float*)d_in[3];
    const float* Ws0 = (const float*)d_in[4];
    const float* bs0 = (const float*)d_in[5];
    const float* Wb0 = (const float*)d_in[6];
    const float* bb0 = (const float*)d_in[7];
    const float* bg0 = (const float*)d_in[8];
    const float* lng1 = (const float*)d_in[9];
    const float* lnb1 = (const float*)d_in[10];
    const float* Ws1 = (const float*)d_in[11];
    const float* bs1 = (const float*)d_in[12];
    const float* Wb1 = (const float*)d_in[13];
    const float* bb1 = (const float*)d_in[14];
    const float* bg1 = (const float*)d_in[15];
    const float* lng2 = (const float*)d_in[16];
    const float* lnb2 = (const float*)d_in[17];
    const float* Ws2 = (const float*)d_in[18];
    const float* bs2 = (const float*)d_in[19];
    const float* Wb2 = (const float*)d_in[20];
    const float* bb2 = (const float*)d_in[21];
    const float* bg2 = (const float*)d_in[22];

    const int N = in_sizes[0] / 128;
    const int E = in_sizes[1] / 2;
    const int NB = (N + 255) >> 8;  // buckets of 256 nodes

    char* wsp = (char*)d_ws;
    size_t off = 0;
    auto alloc = [&](size_t bytes) {
        off = (off + 255) & ~(size_t)255;
        void* p = wsp + off;
        off += bytes;
        return p;
    };
    int* cnt = (int*)alloc((size_t)N * 4);
    int* rowptr = (int*)alloc((size_t)(N + 1) * 4);
    int* bsum = (int*)alloc(1024 * 4);
    int* hmat = (int*)alloc(((size_t)NB * NBLK + 1) * 4);
    int* boff = (int*)alloc((size_t)(NB + 1) * 4);
    int* colv = (int*)alloc((size_t)E * 4);
    float* dinvv = (float*)alloc((size_t)N * 4);
    ushortT* hbuf = (ushortT*)alloc((size_t)N * 128 * 2);
    ushortT* a1 = (ushortT*)alloc((size_t)N * 128 * 2);
    ushortT* a2 = (ushortT*)alloc((size_t)N * 128 * 2);
    float2* stx = (float2*)alloc((size_t)N * 8);
    float2* st1 = (float2*)alloc((size_t)N * 8);
    float2* st2 = (float2*)alloc((size_t)N * 8);
    ushortT* Wc0 = (ushortT*)alloc((size_t)128 * 640 * 2);
    ushortT* Wc1 = (ushortT*)alloc((size_t)128 * 640 * 2);
    ushortT* Wc2 = (ushortT*)alloc((size_t)47 * 1920 * 2);
    size_t off_base = off;
    ushortT* xb = (ushortT*)alloc((size_t)N * 128 * 2);  // bf16 mirror of x
    bool fits = (off <= ws_size);
    if (!fits) off = off_base;
    uint2* ebuf = (uint2*)hbuf;  // aliases hbuf: CSR build completes before fkan writes hbuf
    (void)n_in; (void)out_size;

    const int* srcp = ei;
    const int* dstp = ei + E;

    int gN = (N + 255) / 256;
    int nb = (N + 1023) / 1024;
    int gF = (N + 63) / 64;   // fkan blocks (64 rows)
    int gW = (N + 3) / 4;     // wave-per-node blocks
    int chunk = (E + NBLK - 1) / NBLK;
    int nh = NB * NBLK;
    int nbh = (nh + 1023) / 1024;

    build_wc<<<(128 * 640 + 255) / 256, 256, 0, stream>>>(Ws0, Wb0, Wc0, 128, 128);
    build_wc<<<(128 * 640 + 255) / 256, 256, 0, stream>>>(Ws1, Wb1, Wc1, 128, 128);
    build_wc<<<(47 * 1920 + 255) / 256, 256, 0, stream>>>(Ws2, Wb2, Wc2, 47, 384);

    // CSR build (block-private counting sort; zero global atomics)
    s1_count<<<NBLK, 256, 0, stream>>>(dstp, hmat, E, chunk, N, NB);
    scanA<<<nbh, 256, 0, stream>>>(hmat, hmat, bsum, nh);   // in-place exclusive scan ok? NO -> see below
    scanB<<<1, 64, 0, stream>>>(bsum, nbh);
    scanC<<<nbh, 256, 0, stream>>>(hmat, bsum, nh, E);
    s3_place<<<NBLK, 256, 0, stream>>>(srcp, dstp, hmat, ebuf, E, chunk, N, NB);
    boff_extract<<<(NB + 256) / 256, 256, 0, stream>>>(hmat, boff, NB);
    node_count<<<NB, 256, 0, stream>>>(ebuf, boff, cnt, N);
    scanA<<<nb, 256, 0, stream>>>(cnt, rowptr, bsum, N);
    scanB<<<1, 64, 0, stream>>>(bsum, nb);
    scanC<<<nb, 256, 0, stream>>>(rowptr, bsum, N, E);
    dinv_kernel<<<gN, 256, 0, stream>>>(rowptr, dinvv, N);
    final_fill<<<NB, 256, 0, stream>>>(ebuf, boff, rowptr, colv, N);
    stats_f32<<<gW, 256, 0, stream>>>(x, stx, fits ? xb : nullptr, N);

    // layer 1
    if (fits)
        fkan_kernel<1, 128, 0><<<gF, 256, 0, stream>>>(xb, 128, xb, 128, xb, 128, stx, stx, stx,
                                                       lng0, lnb0, Wc0, bs0, bb0, dinvv, hbuf, 128, N);
    else
        fkan_kernel<1, 128, 1><<<gF, 256, 0, stream>>>(x, 128, x, 128, x, 128, stx, stx, stx,
                                                       lng0, lnb0, Wc0, bs0, bb0, dinvv, hbuf, 128, N);
    agg128_kernel<<<gW, 256, 0, stream>>>(hbuf, a1, bg0, rowptr, colv, dinvv, st1, N);

    // layer 2
    fkan_kernel<1, 128, 0><<<gF, 256, 0, stream>>>(a1, 128, a1, 128, a1, 128, st1, st1, st1,
                                                   lng1, lnb1, Wc1, bs1, bb1, dinvv, hbuf, 128, N);
    agg128_kernel<<<gW, 256, 0, stream>>>(hbuf, a2, bg1, rowptr, colv, dinvv, st2, N);

    // layer 3 (hbuf stride 64)
    if (fits)
        fkan_kernel<3, 47, 0><<<gF, 256, 0, stream>>>(xb, 128, a1, 128, a2, 128, stx, st1, st2,
                                                      lng2, lnb2, Wc2, bs2, bb2, dinvv, hbuf, 64, N);
    else
        fkan_kernel<3, 47, 1><<<gF, 256, 0, stream>>>(x, 128, a1, 128, a2, 128, stx, st1, st2,
                                                      lng2, lnb2, Wc2, bs2, bb2, dinvv, hbuf, 64, N);
    agg47_kernel<<<gW, 256, 0, stream>>>(hbuf, (float*)d_out, bg2, rowptr, colv, dinvv, N);
}

// NOTE on the in-place scanA over hmat: scanA reads its 4 inputs into registers
// BEFORE writing outputs for the same indices (same thread), and blocks only touch
// their own 1024-span, so in-place exclusive scan is safe within scanA. scanC adds
// block offsets computed from bsum (read-only of scanned partials). Cross-block
// ordering is irrelevant because each block's add is independent.